// Round 6
// baseline (398.722 us; speedup 1.0000x reference)
//
#include <hip/hip_runtime.h>
#include <math.h>

// ---------------------------------------------------------------------------
// Detector post-process (YOLO-style), faithful to the JAX reference:
//  decode -> global top-512 (stable desc) -> greedy NMS -> boxes*keep, keep
// R3: two-level LDS radix select (k_hist was 1936us of same-bin atomics)
// R4: split sort/decode; decode = 1 wave/candidate; fold scans + alive
// R5: fuse coarse-hist into scores pass; fuse pairs+nms (matrix in LDS,
//     no global roundtrip). 9 -> 7 dispatches. ~205us is harness poison/
//     restore floor (fills at 84% HBM peak); our kernels ~55us.
// R6: resubmit (R5 bench was an infra failure: container died pre-test)
// ---------------------------------------------------------------------------

#define NCAND 340704          // 32*3*(169+676+2704)
#define NCELL 113568          // 32*(169+676+2704)
#define CAP   4096
#define HELEM 16              // elements per thread in hist kernels
#define CELEM 4               // elements per thread in compact

#define OFF13 0
#define OFF26 16224
#define OFF52 81120
#define CELLS13 5408
#define CELLS26 21632

#define FIND_T 0.5f
#define IOU_T  0.5f
#define DET_T  0.5f
#define DATA_W 416.0f

// ws layout (bytes)
#define WS_SCORES   0u            // float[340704]  = 1,362,816
#define WS_CHIST    1362816u      // u32[256]
#define WS_FHIST    1363840u      // u32[256]
#define WS_COUNTER  1364864u      // u32 (+4 pad)
#define WS_KEYS     1364872u      // u64[4096] = 32,768 (8B aligned)
#define WS_SKEYS    1397640u      // u64[512]  = 4,096
#define WS_CAND6    1401736u      // float[512*6] = 12,288
#define WS_VALID    1414024u      // u32[512] = 2,048

__device__ __forceinline__ unsigned int fmono(float f) {
    unsigned int u = __float_as_uint(f);
    return (u & 0x80000000u) ? ~u : (u | 0x80000000u);
}

// Largest bin t (0..255) whose descending suffix-sum >= need; *above = count
// strictly above that bin. Requires blockDim.x == 256; all threads call.
__device__ int pick_bin256(unsigned int h, unsigned int need, unsigned int* above) {
    __shared__ unsigned int S[256];
    __shared__ int best; __shared__ unsigned int abv;
    int t = threadIdx.x;
    S[t] = h;
    __syncthreads();
    for (int off = 1; off < 256; off <<= 1) {
        unsigned int v = (t + off < 256) ? S[t + off] : 0u;
        __syncthreads();
        S[t] += v;
        __syncthreads();
    }
    if (t == 0) { best = 0; abv = 0; }
    __syncthreads();
    if (S[t] >= need && (t == 255 || S[t + 1] < need)) { best = t; abv = S[t] - h; }
    __syncthreads();
    if (above) *above = abv;
    return best;
}

// ---------------- K1: per-candidate score + fused coarse histogram ---------
__global__ void k_scores_hist(const float* __restrict__ in13,
                              const float* __restrict__ in26,
                              const float* __restrict__ in52,
                              float* __restrict__ scores,
                              unsigned int* __restrict__ chist) {
    __shared__ unsigned int h[256];
    int t = threadIdx.x;
    h[t] = 0;
    __syncthreads();

    int cell = blockIdx.x * blockDim.x + t;
    if (cell < NCELL) {
        const float* in; int SS, b, s, candOff;
        if (cell < CELLS13) {
            in = in13; SS = 169; int l = cell;
            b = l / 169; s = l - b * 169; candOff = OFF13 + l * 3;
        } else if (cell < CELLS13 + CELLS26) {
            in = in26; SS = 676; int l = cell - CELLS13;
            b = l / 676; s = l - b * 676; candOff = OFF26 + l * 3;
        } else {
            in = in52; SS = 2704; int l = cell - (CELLS13 + CELLS26);
            b = l / 2704; s = l - b * 2704; candOff = OFF52 + l * 3;
        }

        for (int a = 0; a < 3; ++a) {
            const float* base = in + (size_t)(b * 255 + a * 85) * (size_t)SS + s;
            float o0  = base[0];
            float obj = 1.0f / (1.0f + expf(-o0));
            float vals[80];
#pragma unroll
            for (int c = 0; c < 80; ++c) vals[c] = base[(size_t)(5 + c) * (size_t)SS];
            float m = vals[0];
#pragma unroll
            for (int c = 1; c < 80; ++c) m = fmaxf(m, vals[c]);
            float sum = 0.0f;
#pragma unroll
            for (int c = 0; c < 80; ++c) sum += expf(vals[c] - m);
            float p = obj * (1.0f / sum);
            float sc = (obj > FIND_T) ? p : -1.0f;
            scores[candOff + a] = sc;
            atomicAdd(&h[fmono(sc) >> 24], 1u);
        }
    }
    __syncthreads();
    if (h[t]) atomicAdd(&chist[t], h[t]);
}

// ---------------- K2: fine 256-bin histogram within coarse bin -------------
__global__ void k_hist_fine(const float* __restrict__ scores,
                            const unsigned int* __restrict__ chist,
                            unsigned int* __restrict__ fhist) {
    __shared__ unsigned int h[256];
    int t = threadIdx.x;
    unsigned int c = (unsigned int)pick_bin256(chist[t], 512u, 0);
    h[t] = 0;
    __syncthreads();
    int base = blockIdx.x * 256 * HELEM;
    for (int e = 0; e < HELEM; ++e) {
        int i = base + e * 256 + t;
        if (i < NCAND) {
            unsigned int mono = fmono(scores[i]);
            if ((mono >> 24) == c) atomicAdd(&h[(mono >> 16) & 0xFFu], 1u);
        }
    }
    __syncthreads();
    if (h[t]) atomicAdd(&fhist[t], h[t]);
}

// ---------------- K3: compact candidates above threshold -------------------
__global__ void k_compact(const float* __restrict__ scores,
                          const unsigned int* __restrict__ chist,
                          const unsigned int* __restrict__ fhist,
                          unsigned int* __restrict__ counter,
                          unsigned long long* __restrict__ keys) {
    int t = threadIdx.x;
    unsigned int above;
    unsigned int c = (unsigned int)pick_bin256(chist[t], 512u, &above);
    unsigned int f = (unsigned int)pick_bin256(fhist[t], 512u - above, 0);
    unsigned int T = (c << 8) | f;

    int base = blockIdx.x * 256 * CELEM;
    for (int e = 0; e < CELEM; ++e) {
        int i = base + e * 256 + t;
        if (i < NCAND) {
            unsigned int mono = fmono(scores[i]);
            if ((mono >> 16) >= T) {
                unsigned int pos = atomicAdd(counter, 1u);
                if (pos < CAP)
                    keys[pos] = ((unsigned long long)mono << 32) |
                                (unsigned int)(~(unsigned int)i);
            }
        }
    }
}

// ---------------- K4: bitonic sort, emit sorted top-512 keys ---------------
__global__ void k_sort(const unsigned long long* __restrict__ keysg,
                       const unsigned int* __restrict__ counter,
                       unsigned long long* __restrict__ sorted) {
    __shared__ unsigned long long keys[CAP];
    int tid = threadIdx.x;
    unsigned int n = *counter; if (n > CAP) n = CAP;
    for (int t = tid; t < CAP; t += 1024)
        keys[t] = (t < (int)n) ? keysg[t] : 0ULL;
    __syncthreads();

    int sz = 1024;
    while ((unsigned)sz < n) sz <<= 1;   // 1024, 2048, or 4096

    for (int k = 2; k <= sz; k <<= 1) {
        for (int j = k >> 1; j > 0; j >>= 1) {
            for (int t = tid; t < (sz >> 1); t += 1024) {
                int i   = ((t & ~(j - 1)) << 1) | (t & (j - 1));
                int ixj = i | j;
                bool dir = ((i & k) == 0);        // descending segment
                unsigned long long x = keys[i], y = keys[ixj];
                if ((x < y) == dir) { keys[i] = y; keys[ixj] = x; }
            }
            __syncthreads();
        }
    }
    if (tid < 512) sorted[tid] = keys[tid];
}

// ---------------- K5: decode top-512, one wave per candidate ---------------
__global__ void k_decode(const unsigned long long* __restrict__ sorted,
                         const float* __restrict__ in13,
                         const float* __restrict__ in26,
                         const float* __restrict__ in52,
                         const float* __restrict__ a13,
                         const float* __restrict__ a26,
                         const float* __restrict__ a52,
                         const float* __restrict__ c1p,
                         const float* __restrict__ c2p,
                         float* __restrict__ cand6,
                         unsigned int* __restrict__ valid) {
    int w = blockIdx.x * (blockDim.x >> 6) + (threadIdx.x >> 6);
    int lane = threadIdx.x & 63;
    if (w >= 512) return;

    unsigned long long key = sorted[w];
    int g = (int)(~(unsigned int)(key & 0xFFFFFFFFULL));

    const float* in; const float* anch; int S, SS, l;
    if (g < OFF26)      { in = in13; anch = a13; S = 13; SS = 169;  l = g - OFF13; }
    else if (g < OFF52) { in = in26; anch = a26; S = 26; SS = 676;  l = g - OFF26; }
    else                { in = in52; anch = a52; S = 52; SS = 2704; l = g - OFF52; }
    int a = l % 3; int cell = l / 3;
    int b = cell / SS; int s = cell - b * SS;
    int y = s / S; int x = s - y * S;

    const float* base = in + (size_t)(b * 255 + a * 85) * (size_t)SS + s;

    // lanes 0..4 load header o0..o4; every lane loads class value c=lane;
    // lanes 0..15 also load c=64+lane
    float hdr  = (lane < 5) ? base[(size_t)lane * (size_t)SS] : 0.0f;
    float val0 = base[(size_t)(5 + lane) * (size_t)SS];
    float val1 = (lane < 16) ? base[(size_t)(69 + lane) * (size_t)SS] : -INFINITY;

    // wave max
    float mx = fmaxf(val0, val1);
#pragma unroll
    for (int o = 32; o; o >>= 1) mx = fmaxf(mx, __shfl_xor(mx, o, 64));
    // first-occurrence argmax (jnp.argmax semantics)
    int i0 = (val0 == mx) ? lane : 1000;
    int i1 = (val1 == mx) ? lane + 64 : 1000;
    int li = i0 < i1 ? i0 : i1;
#pragma unroll
    for (int o = 32; o; o >>= 1) { int v = __shfl_xor(li, o, 64); li = v < li ? v : li; }
    // softmax denominator
    float e = expf(val0 - mx) + ((lane < 16) ? expf(val1 - mx) : 0.0f);
#pragma unroll
    for (int o = 32; o; o >>= 1) e += __shfl_xor(e, o, 64);

    float o0 = __shfl(hdr, 0, 64);
    float o1 = __shfl(hdr, 1, 64);
    float o2 = __shfl(hdr, 2, 64);
    float o3 = __shfl(hdr, 3, 64);
    float o4 = __shfl(hdr, 4, 64);

    if (lane == 0) {
        float c1 = *c1p, c2 = *c2p;
        float obj = 1.0f / (1.0f + expf(-o0));
        float p = obj * (1.0f / e);
        float sgrid = DATA_W / (float)S;   // exact: 32, 16, 8
        cand6[w * 6 + 0] = p;
        cand6[w * 6 + 1] = ((float)x + o1) * sgrid / c1;
        cand6[w * 6 + 2] = ((float)y + o2) * sgrid / c2;
        cand6[w * 6 + 3] = expf(o3) * anch[a * 2 + 0] / c1;
        cand6[w * 6 + 4] = expf(o4) * anch[a * 2 + 1] / c2;
        cand6[w * 6 + 5] = (float)li;
        valid[w] = ((unsigned int)(key >> 32) > 0x80000000u) ? 1u : 0u;
    }
}

// ---------------- K6: pairs matrix (LDS) + greedy NMS + output, fused ------
__global__ __launch_bounds__(1024) void k_pairs_nms(
        const float* __restrict__ cand6,
        const unsigned int* __restrict__ valid,
        float* __restrict__ out) {
    __shared__ unsigned char m[512 * 64];       // 32 KB suppression matrix
    __shared__ float c6[512 * 6];               // 12 KB candidates
    __shared__ unsigned int vbuf[512];          //  2 KB
    __shared__ unsigned char keepbits[64];
    int t = threadIdx.x;

    for (int i = t; i < 512 * 6; i += 1024) c6[i] = cand6[i];
    for (int i = t; i < 512; i += 1024) vbuf[i] = valid[i];
    __syncthreads();

    // pairs: each thread computes 32 matrix bytes
    for (int idx = t; idx < 512 * 64; idx += 1024) {
        int i = idx >> 6, l = idx & 63;
        float cxi = c6[i * 6 + 1], cyi = c6[i * 6 + 2];
        float wi  = c6[i * 6 + 3], hi  = c6[i * 6 + 4];
        float ci  = c6[i * 6 + 5];
        float x1i = cxi - wi / 2.0f, y1i = cyi - hi / 2.0f;
        float x2i = x1i + wi,        y2i = y1i + hi;
        float ai  = (x2i - x1i) * (y2i - y1i);

        unsigned int byte = 0;
#pragma unroll
        for (int b = 0; b < 8; ++b) {
            int j = l * 8 + b;
            if (j > i) {
                float cxj = c6[j * 6 + 1], cyj = c6[j * 6 + 2];
                float wj  = c6[j * 6 + 3], hj  = c6[j * 6 + 4];
                float cj  = c6[j * 6 + 5];
                bool sup = (ci == cj);
                if (!sup) {
                    float x1j = cxj - wj / 2.0f, y1j = cyj - hj / 2.0f;
                    float x2j = x1j + wj,        y2j = y1j + hj;
                    float aj  = (x2j - x1j) * (y2j - y1j);
                    float iw = fminf(x2i, x2j) - fmaxf(x1i, x1j); iw = fmaxf(iw, 0.0f);
                    float ih = fminf(y2i, y2j) - fmaxf(y1i, y1j); ih = fmaxf(ih, 0.0f);
                    float inter = iw * ih;
                    float iou = inter / (ai + aj - inter);
                    sup = (iou >= IOU_T);
                }
                byte |= ((unsigned int)sup) << b;
            }
        }
        m[idx] = (unsigned char)byte;
    }
    __syncthreads();

    // greedy NMS: wave 0 only
    if (t < 64) {
        int lane = t;
        float maxp = vbuf[0] ? c6[0] : 0.0f;
        unsigned int state = 0;                 // suppressed, cols 8*lane..+7
#pragma unroll
        for (int b = 0; b < 8; ++b) {
            int r = lane * 8 + b;
            bool alive = vbuf[r] && (c6[r * 6] > DET_T * maxp);
            if (!alive) state |= 1u << b;
        }
        unsigned int keepmask = 0;
        for (int i = 0; i < 512; ++i) {
            int srcl = i >> 3, bit = i & 7;
            unsigned int sb = (unsigned int)__shfl((int)state, srcl, 64);
            bool active = ((sb >> bit) & 1u) == 0u;
            if (lane == srcl && active) keepmask |= 1u << bit;
            if (active) state |= (unsigned int)m[i * 64 + lane];
        }
        keepbits[lane] = (unsigned char)keepmask;
    }
    __syncthreads();

    // output
    for (int idx = t; idx < 512 * 6; idx += 1024) {
        int r = idx / 6;
        float k = ((keepbits[r >> 3] >> (r & 7)) & 1u) ? 1.0f : 0.0f;
        out[idx] = c6[idx] * k;
    }
    for (int r = t; r < 512; r += 1024) {
        out[512 * 6 + r] = ((keepbits[r >> 3] >> (r & 7)) & 1u) ? 1.0f : 0.0f;
    }
}

// ---------------------------------------------------------------------------
extern "C" void kernel_launch(void* const* d_in, const int* in_sizes, int n_in,
                              void* d_out, int out_size, void* d_ws, size_t ws_size,
                              hipStream_t stream) {
    (void)in_sizes; (void)n_in; (void)out_size; (void)ws_size;
    const float* in13 = (const float*)d_in[0];
    const float* in26 = (const float*)d_in[1];
    const float* in52 = (const float*)d_in[2];
    const float* a13  = (const float*)d_in[3];
    const float* a26  = (const float*)d_in[4];
    const float* a52  = (const float*)d_in[5];
    const float* c1p  = (const float*)d_in[6];
    const float* c2p  = (const float*)d_in[7];

    char* wsb = (char*)d_ws;
    float* scores             = (float*)(wsb + WS_SCORES);
    unsigned int* chist       = (unsigned int*)(wsb + WS_CHIST);
    unsigned int* fhist       = (unsigned int*)(wsb + WS_FHIST);
    unsigned int* counter     = (unsigned int*)(wsb + WS_COUNTER);
    unsigned long long* keys  = (unsigned long long*)(wsb + WS_KEYS);
    unsigned long long* skeys = (unsigned long long*)(wsb + WS_SKEYS);
    float* cand6              = (float*)(wsb + WS_CAND6);
    unsigned int* valid       = (unsigned int*)(wsb + WS_VALID);

    // zero chist + fhist + counter
    hipMemsetAsync(wsb + WS_CHIST, 0, 1024 + 1024 + 8, stream);

    const int hblocks = (NCAND + 256 * HELEM - 1) / (256 * HELEM);  // 84
    const int cblocks = (NCAND + 256 * CELEM - 1) / (256 * CELEM);  // 333

    k_scores_hist<<<(NCELL + 255) / 256, 256, 0, stream>>>(in13, in26, in52,
                                                           scores, chist);
    k_hist_fine<<<hblocks, 256, 0, stream>>>(scores, chist, fhist);
    k_compact<<<cblocks, 256, 0, stream>>>(scores, chist, fhist, counter, keys);
    k_sort<<<1, 1024, 0, stream>>>(keys, counter, skeys);
    k_decode<<<128, 256, 0, stream>>>(skeys, in13, in26, in52,
                                      a13, a26, a52, c1p, c2p, cand6, valid);
    k_pairs_nms<<<1, 1024, 0, stream>>>(cand6, valid, (float*)d_out);
}

// Round 7
// 258.229 us; speedup vs baseline: 1.5441x; 1.5441x over previous
//
#include <hip/hip_runtime.h>
#include <math.h>

// ---------------------------------------------------------------------------
// Detector post-process (YOLO-style), faithful to the JAX reference:
//  decode -> global top-512 (stable desc) -> greedy NMS -> boxes*keep, keep
// R3: two-level LDS radix select (k_hist was 1936us of same-bin atomics)
// R4: split sort/decode; decode = 1 wave/candidate; fold scans + alive
// R5/R6: fuse coarse-hist into scores pass (kept); fuse pairs+nms (REVERTED:
//     192us! 32-way LDS bank conflicts (48l mod 32 = 2 banks) + single-CU
//     serialization of 512^2 IoUs. Split version: 128 blocks + L2 = ~8us)
// R7: k_pairs (global matrix) + k_nms (1 wave) restored from R4.
// ---------------------------------------------------------------------------

#define NCAND 340704          // 32*3*(169+676+2704)
#define NCELL 113568          // 32*(169+676+2704)
#define CAP   4096
#define HELEM 16              // elements per thread in hist kernels
#define CELEM 4               // elements per thread in compact

#define OFF13 0
#define OFF26 16224
#define OFF52 81120
#define CELLS13 5408
#define CELLS26 21632

#define FIND_T 0.5f
#define IOU_T  0.5f
#define DET_T  0.5f
#define DATA_W 416.0f

// ws layout (bytes)
#define WS_SCORES   0u            // float[340704]  = 1,362,816
#define WS_CHIST    1362816u      // u32[256]
#define WS_FHIST    1363840u      // u32[256]
#define WS_COUNTER  1364864u      // u32 (+4 pad)
#define WS_KEYS     1364872u      // u64[4096] = 32,768 (8B aligned)
#define WS_SKEYS    1397640u      // u64[512]  = 4,096
#define WS_CAND6    1401736u      // float[512*6] = 12,288
#define WS_VALID    1414024u      // u32[512] = 2,048
#define WS_MATRIX   1416072u      // u8[512*64] = 32,768

__device__ __forceinline__ unsigned int fmono(float f) {
    unsigned int u = __float_as_uint(f);
    return (u & 0x80000000u) ? ~u : (u | 0x80000000u);
}

// Largest bin t (0..255) whose descending suffix-sum >= need; *above = count
// strictly above that bin. Requires blockDim.x == 256; all threads call.
__device__ int pick_bin256(unsigned int h, unsigned int need, unsigned int* above) {
    __shared__ unsigned int S[256];
    __shared__ int best; __shared__ unsigned int abv;
    int t = threadIdx.x;
    S[t] = h;
    __syncthreads();
    for (int off = 1; off < 256; off <<= 1) {
        unsigned int v = (t + off < 256) ? S[t + off] : 0u;
        __syncthreads();
        S[t] += v;
        __syncthreads();
    }
    if (t == 0) { best = 0; abv = 0; }
    __syncthreads();
    if (S[t] >= need && (t == 255 || S[t + 1] < need)) { best = t; abv = S[t] - h; }
    __syncthreads();
    if (above) *above = abv;
    return best;
}

// ---------------- K1: per-candidate score + fused coarse histogram ---------
__global__ void k_scores_hist(const float* __restrict__ in13,
                              const float* __restrict__ in26,
                              const float* __restrict__ in52,
                              float* __restrict__ scores,
                              unsigned int* __restrict__ chist) {
    __shared__ unsigned int h[256];
    int t = threadIdx.x;
    h[t] = 0;
    __syncthreads();

    int cell = blockIdx.x * blockDim.x + t;
    if (cell < NCELL) {
        const float* in; int SS, b, s, candOff;
        if (cell < CELLS13) {
            in = in13; SS = 169; int l = cell;
            b = l / 169; s = l - b * 169; candOff = OFF13 + l * 3;
        } else if (cell < CELLS13 + CELLS26) {
            in = in26; SS = 676; int l = cell - CELLS13;
            b = l / 676; s = l - b * 676; candOff = OFF26 + l * 3;
        } else {
            in = in52; SS = 2704; int l = cell - (CELLS13 + CELLS26);
            b = l / 2704; s = l - b * 2704; candOff = OFF52 + l * 3;
        }

        for (int a = 0; a < 3; ++a) {
            const float* base = in + (size_t)(b * 255 + a * 85) * (size_t)SS + s;
            float o0  = base[0];
            float obj = 1.0f / (1.0f + expf(-o0));
            float vals[80];
#pragma unroll
            for (int c = 0; c < 80; ++c) vals[c] = base[(size_t)(5 + c) * (size_t)SS];
            float m = vals[0];
#pragma unroll
            for (int c = 1; c < 80; ++c) m = fmaxf(m, vals[c]);
            float sum = 0.0f;
#pragma unroll
            for (int c = 0; c < 80; ++c) sum += expf(vals[c] - m);
            float p = obj * (1.0f / sum);
            float sc = (obj > FIND_T) ? p : -1.0f;
            scores[candOff + a] = sc;
            atomicAdd(&h[fmono(sc) >> 24], 1u);
        }
    }
    __syncthreads();
    if (h[t]) atomicAdd(&chist[t], h[t]);
}

// ---------------- K2: fine 256-bin histogram within coarse bin -------------
__global__ void k_hist_fine(const float* __restrict__ scores,
                            const unsigned int* __restrict__ chist,
                            unsigned int* __restrict__ fhist) {
    __shared__ unsigned int h[256];
    int t = threadIdx.x;
    unsigned int c = (unsigned int)pick_bin256(chist[t], 512u, 0);
    h[t] = 0;
    __syncthreads();
    int base = blockIdx.x * 256 * HELEM;
    for (int e = 0; e < HELEM; ++e) {
        int i = base + e * 256 + t;
        if (i < NCAND) {
            unsigned int mono = fmono(scores[i]);
            if ((mono >> 24) == c) atomicAdd(&h[(mono >> 16) & 0xFFu], 1u);
        }
    }
    __syncthreads();
    if (h[t]) atomicAdd(&fhist[t], h[t]);
}

// ---------------- K3: compact candidates above threshold -------------------
__global__ void k_compact(const float* __restrict__ scores,
                          const unsigned int* __restrict__ chist,
                          const unsigned int* __restrict__ fhist,
                          unsigned int* __restrict__ counter,
                          unsigned long long* __restrict__ keys) {
    int t = threadIdx.x;
    unsigned int above;
    unsigned int c = (unsigned int)pick_bin256(chist[t], 512u, &above);
    unsigned int f = (unsigned int)pick_bin256(fhist[t], 512u - above, 0);
    unsigned int T = (c << 8) | f;

    int base = blockIdx.x * 256 * CELEM;
    for (int e = 0; e < CELEM; ++e) {
        int i = base + e * 256 + t;
        if (i < NCAND) {
            unsigned int mono = fmono(scores[i]);
            if ((mono >> 16) >= T) {
                unsigned int pos = atomicAdd(counter, 1u);
                if (pos < CAP)
                    keys[pos] = ((unsigned long long)mono << 32) |
                                (unsigned int)(~(unsigned int)i);
            }
        }
    }
}

// ---------------- K4: bitonic sort, emit sorted top-512 keys ---------------
__global__ void k_sort(const unsigned long long* __restrict__ keysg,
                       const unsigned int* __restrict__ counter,
                       unsigned long long* __restrict__ sorted) {
    __shared__ unsigned long long keys[CAP];
    int tid = threadIdx.x;
    unsigned int n = *counter; if (n > CAP) n = CAP;
    for (int t = tid; t < CAP; t += 1024)
        keys[t] = (t < (int)n) ? keysg[t] : 0ULL;
    __syncthreads();

    int sz = 1024;
    while ((unsigned)sz < n) sz <<= 1;   // 1024, 2048, or 4096

    for (int k = 2; k <= sz; k <<= 1) {
        for (int j = k >> 1; j > 0; j >>= 1) {
            for (int t = tid; t < (sz >> 1); t += 1024) {
                int i   = ((t & ~(j - 1)) << 1) | (t & (j - 1));
                int ixj = i | j;
                bool dir = ((i & k) == 0);        // descending segment
                unsigned long long x = keys[i], y = keys[ixj];
                if ((x < y) == dir) { keys[i] = y; keys[ixj] = x; }
            }
            __syncthreads();
        }
    }
    if (tid < 512) sorted[tid] = keys[tid];
}

// ---------------- K5: decode top-512, one wave per candidate ---------------
__global__ void k_decode(const unsigned long long* __restrict__ sorted,
                         const float* __restrict__ in13,
                         const float* __restrict__ in26,
                         const float* __restrict__ in52,
                         const float* __restrict__ a13,
                         const float* __restrict__ a26,
                         const float* __restrict__ a52,
                         const float* __restrict__ c1p,
                         const float* __restrict__ c2p,
                         float* __restrict__ cand6,
                         unsigned int* __restrict__ valid) {
    int w = blockIdx.x * (blockDim.x >> 6) + (threadIdx.x >> 6);
    int lane = threadIdx.x & 63;
    if (w >= 512) return;

    unsigned long long key = sorted[w];
    int g = (int)(~(unsigned int)(key & 0xFFFFFFFFULL));

    const float* in; const float* anch; int S, SS, l;
    if (g < OFF26)      { in = in13; anch = a13; S = 13; SS = 169;  l = g - OFF13; }
    else if (g < OFF52) { in = in26; anch = a26; S = 26; SS = 676;  l = g - OFF26; }
    else                { in = in52; anch = a52; S = 52; SS = 2704; l = g - OFF52; }
    int a = l % 3; int cell = l / 3;
    int b = cell / SS; int s = cell - b * SS;
    int y = s / S; int x = s - y * S;

    const float* base = in + (size_t)(b * 255 + a * 85) * (size_t)SS + s;

    // lanes 0..4 load header o0..o4; every lane loads class value c=lane;
    // lanes 0..15 also load c=64+lane
    float hdr  = (lane < 5) ? base[(size_t)lane * (size_t)SS] : 0.0f;
    float val0 = base[(size_t)(5 + lane) * (size_t)SS];
    float val1 = (lane < 16) ? base[(size_t)(69 + lane) * (size_t)SS] : -INFINITY;

    // wave max
    float mx = fmaxf(val0, val1);
#pragma unroll
    for (int o = 32; o; o >>= 1) mx = fmaxf(mx, __shfl_xor(mx, o, 64));
    // first-occurrence argmax (jnp.argmax semantics)
    int i0 = (val0 == mx) ? lane : 1000;
    int i1 = (val1 == mx) ? lane + 64 : 1000;
    int li = i0 < i1 ? i0 : i1;
#pragma unroll
    for (int o = 32; o; o >>= 1) { int v = __shfl_xor(li, o, 64); li = v < li ? v : li; }
    // softmax denominator
    float e = expf(val0 - mx) + ((lane < 16) ? expf(val1 - mx) : 0.0f);
#pragma unroll
    for (int o = 32; o; o >>= 1) e += __shfl_xor(e, o, 64);

    float o0 = __shfl(hdr, 0, 64);
    float o1 = __shfl(hdr, 1, 64);
    float o2 = __shfl(hdr, 2, 64);
    float o3 = __shfl(hdr, 3, 64);
    float o4 = __shfl(hdr, 4, 64);

    if (lane == 0) {
        float c1 = *c1p, c2 = *c2p;
        float obj = 1.0f / (1.0f + expf(-o0));
        float p = obj * (1.0f / e);
        float sgrid = DATA_W / (float)S;   // exact: 32, 16, 8
        cand6[w * 6 + 0] = p;
        cand6[w * 6 + 1] = ((float)x + o1) * sgrid / c1;
        cand6[w * 6 + 2] = ((float)y + o2) * sgrid / c2;
        cand6[w * 6 + 3] = expf(o3) * anch[a * 2 + 0] / c1;
        cand6[w * 6 + 4] = expf(o4) * anch[a * 2 + 1] / c2;
        cand6[w * 6 + 5] = (float)li;
        valid[w] = ((unsigned int)(key >> 32) > 0x80000000u) ? 1u : 0u;
    }
}

// ---------------- K6: pairwise suppression matrix --------------------------
__global__ void k_pairs(const float* __restrict__ cand6,
                        unsigned char* __restrict__ matrix) {
    int t = blockIdx.x * blockDim.x + threadIdx.x;
    if (t >= 512 * 64) return;
    int i = t >> 6, l = t & 63;
    float cxi = cand6[i * 6 + 1], cyi = cand6[i * 6 + 2];
    float wi  = cand6[i * 6 + 3], hi  = cand6[i * 6 + 4];
    float ci  = cand6[i * 6 + 5];
    float x1i = cxi - wi / 2.0f, y1i = cyi - hi / 2.0f;
    float x2i = x1i + wi,        y2i = y1i + hi;
    float ai  = (x2i - x1i) * (y2i - y1i);

    unsigned int byte = 0;
#pragma unroll
    for (int b = 0; b < 8; ++b) {
        int j = l * 8 + b;
        if (j > i) {
            float cxj = cand6[j * 6 + 1], cyj = cand6[j * 6 + 2];
            float wj  = cand6[j * 6 + 3], hj  = cand6[j * 6 + 4];
            float cj  = cand6[j * 6 + 5];
            bool sup = (ci == cj);
            if (!sup) {
                float x1j = cxj - wj / 2.0f, y1j = cyj - hj / 2.0f;
                float x2j = x1j + wj,        y2j = y1j + hj;
                float aj  = (x2j - x1j) * (y2j - y1j);
                float iw = fminf(x2i, x2j) - fmaxf(x1i, x1j); iw = fmaxf(iw, 0.0f);
                float ih = fminf(y2i, y2j) - fmaxf(y1i, y1j); ih = fmaxf(ih, 0.0f);
                float inter = iw * ih;
                float iou = inter / (ai + aj - inter);
                sup = (iou >= IOU_T);
            }
            byte |= ((unsigned int)sup) << b;
        }
    }
    matrix[i * 64 + l] = (unsigned char)byte;
}

// ---------------- K7: sequential greedy NMS (one wave) + output ------------
__global__ void k_nms(const unsigned char* __restrict__ matrix,
                      const unsigned int* __restrict__ valid,
                      const float* __restrict__ cand6,
                      float* __restrict__ out) {
    __shared__ uint4 mbuf[2048];                 // 32 KB
    const unsigned char* m = (const unsigned char*)mbuf;
    int lane = threadIdx.x;                      // 64 threads = 1 wave

    const uint4* src = (const uint4*)matrix;
    for (int t = lane; t < 2048; t += 64) mbuf[t] = src[t];

    float maxp = valid[0] ? cand6[0] : 0.0f;

    unsigned int state = 0;                      // suppressed bits, cols 8*lane..8*lane+7
#pragma unroll
    for (int b = 0; b < 8; ++b) {
        int r = lane * 8 + b;
        bool alive = valid[r] && (cand6[r * 6] > DET_T * maxp);
        if (!alive) state |= 1u << b;
    }
    __syncthreads();

    unsigned int keepmask = 0;
    for (int i = 0; i < 512; ++i) {
        int srcl = i >> 3, bit = i & 7;
        unsigned int sb = (unsigned int)__shfl((int)state, srcl, 64);
        bool active = ((sb >> bit) & 1u) == 0u;
        if (lane == srcl && active) keepmask |= 1u << bit;
        if (active) state |= (unsigned int)m[i * 64 + lane];
    }

#pragma unroll
    for (int b = 0; b < 8; ++b) {
        int r = lane * 8 + b;
        float k = ((keepmask >> b) & 1u) ? 1.0f : 0.0f;
        for (int c = 0; c < 6; ++c) out[r * 6 + c] = cand6[r * 6 + c] * k;
        out[512 * 6 + r] = k;
    }
}

// ---------------------------------------------------------------------------
extern "C" void kernel_launch(void* const* d_in, const int* in_sizes, int n_in,
                              void* d_out, int out_size, void* d_ws, size_t ws_size,
                              hipStream_t stream) {
    (void)in_sizes; (void)n_in; (void)out_size; (void)ws_size;
    const float* in13 = (const float*)d_in[0];
    const float* in26 = (const float*)d_in[1];
    const float* in52 = (const float*)d_in[2];
    const float* a13  = (const float*)d_in[3];
    const float* a26  = (const float*)d_in[4];
    const float* a52  = (const float*)d_in[5];
    const float* c1p  = (const float*)d_in[6];
    const float* c2p  = (const float*)d_in[7];

    char* wsb = (char*)d_ws;
    float* scores             = (float*)(wsb + WS_SCORES);
    unsigned int* chist       = (unsigned int*)(wsb + WS_CHIST);
    unsigned int* fhist       = (unsigned int*)(wsb + WS_FHIST);
    unsigned int* counter     = (unsigned int*)(wsb + WS_COUNTER);
    unsigned long long* keys  = (unsigned long long*)(wsb + WS_KEYS);
    unsigned long long* skeys = (unsigned long long*)(wsb + WS_SKEYS);
    float* cand6              = (float*)(wsb + WS_CAND6);
    unsigned int* valid       = (unsigned int*)(wsb + WS_VALID);
    unsigned char* matrix     = (unsigned char*)(wsb + WS_MATRIX);

    // zero chist + fhist + counter
    hipMemsetAsync(wsb + WS_CHIST, 0, 1024 + 1024 + 8, stream);

    const int hblocks = (NCAND + 256 * HELEM - 1) / (256 * HELEM);  // 84
    const int cblocks = (NCAND + 256 * CELEM - 1) / (256 * CELEM);  // 333

    k_scores_hist<<<(NCELL + 255) / 256, 256, 0, stream>>>(in13, in26, in52,
                                                           scores, chist);
    k_hist_fine<<<hblocks, 256, 0, stream>>>(scores, chist, fhist);
    k_compact<<<cblocks, 256, 0, stream>>>(scores, chist, fhist, counter, keys);
    k_sort<<<1, 1024, 0, stream>>>(keys, counter, skeys);
    k_decode<<<128, 256, 0, stream>>>(skeys, in13, in26, in52,
                                      a13, a26, a52, c1p, c2p, cand6, valid);
    k_pairs<<<128, 256, 0, stream>>>(cand6, matrix);
    k_nms<<<1, 64, 0, stream>>>(matrix, valid, cand6, (float*)d_out);
}